// Round 1
// baseline (249.574 us; speedup 1.0000x reference)
//
#include <hip/hip_runtime.h>
#include <hip/hip_bf16.h>

// Problem constants (from reference setup_inputs): B=8, N=2048, D=512
#define PB 8
#define PN 2048
#define PD 512
#define P_ASEM 0.6f

// ---------------------------------------------------------------------------
// Kernel 1: per-row dots. si[r] = x[r,:].Wi, sj[r] = x[r,:].Wj for r in [0,B*N)
// One wave (64 lanes) per row; each lane handles 8 floats (2x float4),
// then 64-lane shuffle reduction. x read is fully coalesced (16B/lane).
// ---------------------------------------------------------------------------
__global__ __launch_bounds__(256) void row_dots_kernel(
    const float* __restrict__ x,   // [B*N, D]
    const float* __restrict__ W,   // [2*D]
    float* __restrict__ si,        // [B*N]
    float* __restrict__ sj)        // [B*N]
{
    const int wave = threadIdx.x >> 6;            // 0..3
    const int lane = threadIdx.x & 63;
    const int row  = blockIdx.x * 4 + wave;       // 0..B*N-1  (grid = B*N/4)

    const float4* xr = (const float4*)(x + (size_t)row * PD);
    const float4* Wi = (const float4*)(W);
    const float4* Wj = (const float4*)(W + PD);

    // D = 512 floats = 128 float4; 64 lanes -> 2 float4 per lane
    float4 a0  = xr[lane];
    float4 a1  = xr[lane + 64];
    float4 wi0 = Wi[lane];
    float4 wi1 = Wi[lane + 64];
    float4 wj0 = Wj[lane];
    float4 wj1 = Wj[lane + 64];

    float acc_i = a0.x*wi0.x + a0.y*wi0.y + a0.z*wi0.z + a0.w*wi0.w
                + a1.x*wi1.x + a1.y*wi1.y + a1.z*wi1.z + a1.w*wi1.w;
    float acc_j = a0.x*wj0.x + a0.y*wj0.y + a0.z*wj0.z + a0.w*wj0.w
                + a1.x*wj1.x + a1.y*wj1.y + a1.z*wj1.z + a1.w*wj1.w;

    // 64-lane butterfly reduction
    #pragma unroll
    for (int off = 32; off > 0; off >>= 1) {
        acc_i += __shfl_down(acc_i, off, 64);
        acc_j += __shfl_down(acc_j, off, 64);
    }
    if (lane == 0) {
        si[row] = acc_i;
        sj[row] = acc_j;
    }
}

// ---------------------------------------------------------------------------
// Kernel 2: out[b,i,j] = 0.6*sigmoid(si[b,i]+sj[b,j]+b0) + 0.4*adj[b,i,j]
// float4 per thread; streaming adj->out is the HBM-bound part.
// si[row] is wave-uniform (broadcast); sj float4 loads are L2-resident (64KB).
// ---------------------------------------------------------------------------
__device__ __forceinline__ float fsigmoid(float t) {
    return 1.0f / (1.0f + __expf(-t));
}

__global__ __launch_bounds__(256) void blend_kernel(
    const float* __restrict__ adj,  // [B*N*N]
    const float* __restrict__ si,   // [B*N]
    const float* __restrict__ sj,   // [B*N]
    const float* __restrict__ bptr, // [1]
    float* __restrict__ out)        // [B*N*N]
{
    const size_t o = (size_t)blockIdx.x * blockDim.x + threadIdx.x; // float4 idx
    const int row  = (int)(o >> 9);        // / (N/4=512) -> combined b*N+i row
    const int jc   = (int)(o & 511);       // float4 column within row
    const int bidx = row >> 11;            // / N -> batch

    const float s = si[row] + bptr[0];
    const float4 sv = ((const float4*)(sj + (size_t)bidx * PN))[jc];
    const float4 av = ((const float4*)adj)[o];

    float4 r;
    r.x = P_ASEM * fsigmoid(s + sv.x) + (1.0f - P_ASEM) * av.x;
    r.y = P_ASEM * fsigmoid(s + sv.y) + (1.0f - P_ASEM) * av.y;
    r.z = P_ASEM * fsigmoid(s + sv.z) + (1.0f - P_ASEM) * av.z;
    r.w = P_ASEM * fsigmoid(s + sv.w) + (1.0f - P_ASEM) * av.w;

    ((float4*)out)[o] = r;
}

extern "C" void kernel_launch(void* const* d_in, const int* in_sizes, int n_in,
                              void* d_out, int out_size, void* d_ws, size_t ws_size,
                              hipStream_t stream) {
    const float* x   = (const float*)d_in[0];  // [8,2048,512]
    const float* adj = (const float*)d_in[1];  // [8,2048,2048]
    const float* W   = (const float*)d_in[2];  // [1,1024]
    const float* b   = (const float*)d_in[3];  // [1]
    float* out = (float*)d_out;

    float* si = (float*)d_ws;            // B*N = 16384 floats
    float* sj = si + (PB * PN);          // B*N = 16384 floats (128 KB total)

    // Kernel 1: B*N/4 = 4096 blocks of 256 threads (4 waves = 4 rows each)
    row_dots_kernel<<<(PB * PN) / 4, 256, 0, stream>>>(x, W, si, sj);

    // Kernel 2: B*N*N/4 float4 elements = 8,388,608 threads
    const size_t n4 = (size_t)PB * PN * PN / 4;
    blend_kernel<<<(int)(n4 / 256), 256, 0, stream>>>(adj, si, sj, b, out);
}